// Round 2
// baseline (1459.158 us; speedup 1.0000x reference)
//
#include <hip/hip_runtime.h>
#include <cstddef>

#define T_LEN 4096
#define EMB 768
#define NH 12
#define HD 64
#define WIN 512

// ---------------- GEMM f32, 128x128 tile, 8x8 microtile, up to 3 B/C pairs via blockIdx.z.
// C[M,N] = A[M,K] @ B[K,N], row-major. Split fragments (tx, tx+64) keep LDS reads <=2-way.
#define GBM 128
#define GBN 128
#define GBK 16

__global__ __launch_bounds__(256) void gemm3_f32(const float* __restrict__ A,
                                                 const float* __restrict__ B0,
                                                 const float* __restrict__ B1,
                                                 const float* __restrict__ B2,
                                                 float* __restrict__ C0,
                                                 float* __restrict__ C1,
                                                 float* __restrict__ C2,
                                                 int M, int N, int K) {
    __shared__ float As[GBK][GBM + 4];   // A transposed: [k][m]
    __shared__ float Bs[GBK][GBN + 4];   // B row-major:  [k][n]
    const int tid = threadIdx.x;
    const int bm = blockIdx.y * GBM;
    const int bn = blockIdx.x * GBN;
    const float* __restrict__ B = (blockIdx.z == 0) ? B0 : (blockIdx.z == 1) ? B1 : B2;
    float* __restrict__ C = (blockIdx.z == 0) ? C0 : (blockIdx.z == 1) ? C1 : C2;

    const int ty = (tid >> 4) << 2;      // row frag base: rows {ty..ty+3, ty+64..ty+67}
    const int tx = (tid & 15) << 2;      // col frag base: cols {tx..tx+3, tx+64..tx+67}

    const int ar = tid >> 1;             // staging A: row 0..127
    const int ac = (tid & 1) << 3;       // staging A: k base 0 or 8
    const int br = tid >> 4;             // staging B: k row 0..15
    const int bc = (tid & 15) << 3;      // staging B: col base 0..120

    float acc[8][8] = {};

    for (int k0 = 0; k0 < K; k0 += GBK) {
        const float4 a0 = *(const float4*)&A[(size_t)(bm + ar) * K + k0 + ac];
        const float4 a1 = *(const float4*)&A[(size_t)(bm + ar) * K + k0 + ac + 4];
        As[ac + 0][ar] = a0.x; As[ac + 1][ar] = a0.y; As[ac + 2][ar] = a0.z; As[ac + 3][ar] = a0.w;
        As[ac + 4][ar] = a1.x; As[ac + 5][ar] = a1.y; As[ac + 6][ar] = a1.z; As[ac + 7][ar] = a1.w;
        *(float4*)&Bs[br][bc]     = *(const float4*)&B[(size_t)(k0 + br) * N + bn + bc];
        *(float4*)&Bs[br][bc + 4] = *(const float4*)&B[(size_t)(k0 + br) * N + bn + bc + 4];
        __syncthreads();
#pragma unroll
        for (int k = 0; k < GBK; ++k) {
            const float4 a0v = *(const float4*)&As[k][ty];
            const float4 a1v = *(const float4*)&As[k][ty + 64];
            const float4 b0v = *(const float4*)&Bs[k][tx];
            const float4 b1v = *(const float4*)&Bs[k][tx + 64];
            const float av[8] = {a0v.x, a0v.y, a0v.z, a0v.w, a1v.x, a1v.y, a1v.z, a1v.w};
            const float bv[8] = {b0v.x, b0v.y, b0v.z, b0v.w, b1v.x, b1v.y, b1v.z, b1v.w};
#pragma unroll
            for (int i = 0; i < 8; ++i)
#pragma unroll
                for (int j = 0; j < 8; ++j)
                    acc[i][j] += av[i] * bv[j];
        }
        __syncthreads();
    }
#pragma unroll
    for (int i = 0; i < 8; ++i) {
        const int r = bm + ty + ((i < 4) ? i : (60 + i));   // ty+i or ty+64+(i-4)
        *(float4*)&C[(size_t)r * N + bn + tx]      = make_float4(acc[i][0], acc[i][1], acc[i][2], acc[i][3]);
        *(float4*)&C[(size_t)r * N + bn + tx + 64] = make_float4(acc[i][4], acc[i][5], acc[i][6], acc[i][7]);
    }
}

// ---------------- discoverability bias: d[h][t] = K_h[t]·u_h − mean
__global__ __launch_bounds__(256) void dbias_kernel(const float* __restrict__ K,
                                                    const float* __restrict__ u,
                                                    float* __restrict__ d_bias) {
    const int h = blockIdx.x;
    const int tid = threadIdx.x;
    __shared__ __align__(16) float us[HD];
    __shared__ float dr[T_LEN];
    __shared__ float red[256];
    if (tid < HD) us[tid] = u[h * HD + tid];
    __syncthreads();
    const float4* u4 = (const float4*)us;
    float lsum = 0.f;
    for (int t = tid; t < T_LEN; t += 256) {
        const float4* Kp = (const float4*)&K[(size_t)t * EMB + h * HD];
        float acc = 0.f;
#pragma unroll
        for (int i = 0; i < HD / 4; ++i) {
            float4 k4 = Kp[i];
            float4 uu = u4[i];
            acc += k4.x * uu.x + k4.y * uu.y + k4.z * uu.z + k4.w * uu.w;
        }
        dr[t] = acc;
        lsum += acc;
    }
    red[tid] = lsum;
    __syncthreads();
    for (int off = 128; off > 0; off >>= 1) {
        if (tid < off) red[tid] += red[tid + off];
        __syncthreads();
    }
    const float mean = red[0] * (1.0f / (float)T_LEN);
    __syncthreads();
    for (int t = tid; t < T_LEN; t += 256) {
        d_bias[h * T_LEN + t] = dr[t] - mean;
    }
}

// ---------------- tiled banded attention, flash-style online softmax.
// One block per (64-row t-tile, head). 16x16 threads, 4x4 register tiles.
// 4 barriers/chunk: stage Kc+Qc together, fused M1+M2 loop, P-scatter overlapped with V staging.
__global__ __launch_bounds__(256) void attn_band_kernel(const float* __restrict__ Q,
                                                        const float* __restrict__ K,
                                                        const float* __restrict__ V,
                                                        const float* __restrict__ d_bias,
                                                        const float* __restrict__ gates,
                                                        float* __restrict__ attn,
                                                        float* __restrict__ ctx,
                                                        float* __restrict__ row_max,
                                                        float* __restrict__ row_invden) {
    const int t0  = blockIdx.x << 6;
    const int h   = blockIdx.y;
    const int tid = threadIdx.x;
    const int tm  = (tid >> 4) << 2;   // row base within tile (0..60)
    const int tn4 = (tid & 15) << 2;   // col base within chunk (0..60)
    const int lm  = tid >> 2;          // staging: row 0..63
    const int lk  = (tid & 3) << 2;    // staging: k base 0..12

    __shared__ __align__(16) float QT[64][68];  // Q[t0+m][k] -> QT[k][m]
    __shared__ __align__(16) float KT[64][68];  // K[t0+m][k] -> KT[k][m]
    __shared__ __align__(16) float Cc[64][68];  // K chunk transposed / P (time-shared)
    __shared__ __align__(16) float Qs[64][68];  // Q chunk transposed / V row-major (time-shared)

    // per-head gate softmax (fold 1/sqrt(64) into w_std/w_rec)
    const float g0 = gates[h * 3 + 0];
    const float g1 = gates[h * 3 + 1];
    const float g2 = gates[h * 3 + 2];
    const float gm = fmaxf(g0, fmaxf(g1, g2));
    const float e0 = __expf(g0 - gm), e1 = __expf(g1 - gm), e2 = __expf(g2 - gm);
    const float gi = 1.0f / (e0 + e1 + e2);
    const float w_std = e0 * gi * 0.125f;
    const float w_rec = e1 * gi * 0.125f;
    const float w_disc = e2 * gi;

    // stage this tile's Q and K rows, transposed to [k][m]
    {
        const float* Qp = Q + (size_t)(t0 + lm) * EMB + h * HD + lk;
        const float* Kp = K + (size_t)(t0 + lm) * EMB + h * HD + lk;
#pragma unroll
        for (int it = 0; it < 4; ++it) {
            float4 a = *(const float4*)(Qp + 16 * it);
            QT[lk + 16 * it + 0][lm] = a.x;
            QT[lk + 16 * it + 1][lm] = a.y;
            QT[lk + 16 * it + 2][lm] = a.z;
            QT[lk + 16 * it + 3][lm] = a.w;
            float4 b = *(const float4*)(Kp + 16 * it);
            KT[lk + 16 * it + 0][lm] = b.x;
            KT[lk + 16 * it + 1][lm] = b.y;
            KT[lk + 16 * it + 2][lm] = b.z;
            KT[lk + 16 * it + 3][lm] = b.w;
        }
    }

    const int s_base = (t0 - WIN > 0) ? (t0 - WIN) : 0;
    const int nch = ((t0 + 64) - s_base) >> 6;   // <= 9 chunks

    float rm[4], rden[4], acc[4][4];
#pragma unroll
    for (int i = 0; i < 4; ++i) {
        rm[i] = -1e30f;
        rden[i] = 0.f;
#pragma unroll
        for (int j = 0; j < 4; ++j) acc[i][j] = 0.f;
    }

    for (int c = 0; c < nch; ++c) {
        const int s0 = s_base + (c << 6);
        __syncthreads();   // (1) prev chunk's PV reads done; QT/KT staging visible on c==0
        // stage K chunk and Q chunk, both transposed [k][m]
        {
            const float* Kp = K + (size_t)(s0 + lm) * EMB + h * HD + lk;
            const float* Qp = Q + (size_t)(s0 + lm) * EMB + h * HD + lk;
#pragma unroll
            for (int it = 0; it < 4; ++it) {
                float4 b = *(const float4*)(Kp + 16 * it);
                Cc[lk + 16 * it + 0][lm] = b.x;
                Cc[lk + 16 * it + 1][lm] = b.y;
                Cc[lk + 16 * it + 2][lm] = b.z;
                Cc[lk + 16 * it + 3][lm] = b.w;
                float4 q = *(const float4*)(Qp + 16 * it);
                Qs[lk + 16 * it + 0][lm] = q.x;
                Qs[lk + 16 * it + 1][lm] = q.y;
                Qs[lk + 16 * it + 2][lm] = q.z;
                Qs[lk + 16 * it + 3][lm] = q.w;
            }
        }
        __syncthreads();   // (2)

        // fused: M1[i][j] = Q[t0+tm+i].K[s0+tn4+j],  M2[i][j] = K[t0+tm+i].Q[s0+tn4+j]
        float m1[4][4] = {};
        float m2[4][4] = {};
#pragma unroll 8
        for (int k = 0; k < 64; ++k) {
            const float4 aq = *(const float4*)&QT[k][tm];
            const float4 bk = *(const float4*)&Cc[k][tn4];
            const float4 ak = *(const float4*)&KT[k][tm];
            const float4 bq = *(const float4*)&Qs[k][tn4];
            m1[0][0] += aq.x * bk.x; m1[0][1] += aq.x * bk.y; m1[0][2] += aq.x * bk.z; m1[0][3] += aq.x * bk.w;
            m1[1][0] += aq.y * bk.x; m1[1][1] += aq.y * bk.y; m1[1][2] += aq.y * bk.z; m1[1][3] += aq.y * bk.w;
            m1[2][0] += aq.z * bk.x; m1[2][1] += aq.z * bk.y; m1[2][2] += aq.z * bk.z; m1[2][3] += aq.z * bk.w;
            m1[3][0] += aq.w * bk.x; m1[3][1] += aq.w * bk.y; m1[3][2] += aq.w * bk.z; m1[3][3] += aq.w * bk.w;
            m2[0][0] += ak.x * bq.x; m2[0][1] += ak.x * bq.y; m2[0][2] += ak.x * bq.z; m2[0][3] += ak.x * bq.w;
            m2[1][0] += ak.y * bq.x; m2[1][1] += ak.y * bq.y; m2[1][2] += ak.y * bq.z; m2[1][3] += ak.y * bq.w;
            m2[2][0] += ak.z * bq.x; m2[2][1] += ak.z * bq.y; m2[2][2] += ak.z * bq.z; m2[2][3] += ak.z * bq.w;
            m2[3][0] += ak.w * bq.x; m2[3][1] += ak.w * bq.y; m2[3][2] += ak.w * bq.z; m2[3][3] += ak.w * bq.w;
        }

        // logits + band mask + raw store + online softmax state
        const float4 db = *(const float4*)&d_bias[h * T_LEN + s0 + tn4];
        float l[4][4];
#pragma unroll
        for (int i = 0; i < 4; ++i) {
            const int t = t0 + tm + i;
            const float dbv[4] = {db.x, db.y, db.z, db.w};
#pragma unroll
            for (int j = 0; j < 4; ++j) {
                const int s = s0 + tn4 + j;
                float lv = w_std * m1[i][j] + w_rec * m2[i][j] + w_disc * dbv[j];
                const bool valid = (s <= t) && (s >= t - WIN);
                l[i][j] = valid ? lv : -1e30f;
            }
            *(float4*)&attn[((size_t)(h * T_LEN + t)) * T_LEN + s0 + tn4] =
                make_float4(l[i][0], l[i][1], l[i][2], l[i][3]);
        }
        // chunk row max across the 16 lanes owning each row
        float cmx[4];
#pragma unroll
        for (int i = 0; i < 4; ++i)
            cmx[i] = fmaxf(fmaxf(l[i][0], l[i][1]), fmaxf(l[i][2], l[i][3]));
#pragma unroll
        for (int off = 1; off < 16; off <<= 1) {
#pragma unroll
            for (int i = 0; i < 4; ++i) cmx[i] = fmaxf(cmx[i], __shfl_xor(cmx[i], off));
        }
        // online update: rescale den/ctx, l -> p
        float cs[4];
#pragma unroll
        for (int i = 0; i < 4; ++i) {
            const float nm = fmaxf(rm[i], cmx[i]);
            const float f = __expf(rm[i] - nm);
            float s = 0.f;
#pragma unroll
            for (int j = 0; j < 4; ++j) {
                const float p = __expf(l[i][j] - nm);
                l[i][j] = p;
                s += p;
            }
            cs[i] = s;
            rm[i] = nm;
            rden[i] *= f;
#pragma unroll
            for (int j = 0; j < 4; ++j) acc[i][j] *= f;
        }
#pragma unroll
        for (int off = 1; off < 16; off <<= 1) {
#pragma unroll
            for (int i = 0; i < 4; ++i) cs[i] += __shfl_xor(cs[i], off);
        }
#pragma unroll
        for (int i = 0; i < 4; ++i) rden[i] += cs[i];

        __syncthreads();   // (3) all reads of Cc/Qs done
        // scatter P into Cc as [k][m]; stage V chunk into Qs row-major [s][d]
#pragma unroll
        for (int i = 0; i < 4; ++i)
#pragma unroll
            for (int j = 0; j < 4; ++j)
                Cc[tn4 + j][tm + i] = l[i][j];
        {
            const float* Vp = V + (size_t)(s0 + lm) * EMB + h * HD + lk;
#pragma unroll
            for (int it = 0; it < 4; ++it)
                *(float4*)&Qs[lm][lk + 16 * it] = *(const float4*)(Vp + 16 * it);
        }
        __syncthreads();   // (4)

        // ctx += P @ V
#pragma unroll 16
        for (int k = 0; k < 64; ++k) {
            const float4 av = *(const float4*)&Cc[k][tm];
            const float4 bv = *(const float4*)&Qs[k][tn4];
            acc[0][0] += av.x * bv.x; acc[0][1] += av.x * bv.y; acc[0][2] += av.x * bv.z; acc[0][3] += av.x * bv.w;
            acc[1][0] += av.y * bv.x; acc[1][1] += av.y * bv.y; acc[1][2] += av.y * bv.z; acc[1][3] += av.y * bv.w;
            acc[2][0] += av.z * bv.x; acc[2][1] += av.z * bv.y; acc[2][2] += av.z * bv.z; acc[2][3] += av.z * bv.w;
            acc[3][0] += av.w * bv.x; acc[3][1] += av.w * bv.y; acc[3][2] += av.w * bv.z; acc[3][3] += av.w * bv.w;
        }
    }

    // epilogue: ctx and per-row stats
#pragma unroll
    for (int i = 0; i < 4; ++i) {
        const float idv = 1.0f / rden[i];
        *(float4*)&ctx[(size_t)(t0 + tm + i) * EMB + h * HD + tn4] =
            make_float4(acc[i][0] * idv, acc[i][1] * idv, acc[i][2] * idv, acc[i][3] * idv);
        if ((tid & 15) == 0) {
            row_max[h * T_LEN + t0 + tm + i] = rm[i];
            row_invden[h * T_LEN + t0 + tm + i] = idv;
        }
    }
}

// ---------------- normalize band + zero-fill full attn rows (streaming, write-BW-bound)
__global__ __launch_bounds__(256) void attn_norm_kernel(float* __restrict__ attn,
                                                        const float* __restrict__ row_max,
                                                        const float* __restrict__ row_invden) {
    const int t = blockIdx.x;
    const int h = blockIdx.y;
    const float m   = row_max[h * T_LEN + t];
    const float idv = row_invden[h * T_LEN + t];
    float* arow = attn + ((size_t)(h * T_LEN + t)) * T_LEN;
    const int bl = (t - WIN > 0) ? (t - WIN) : 0;
    for (int i4 = threadIdx.x << 2; i4 < T_LEN; i4 += 1024) {
        float4 v = make_float4(0.f, 0.f, 0.f, 0.f);
        if (i4 + 3 >= bl && i4 <= t) {
            const float4 r = *(const float4*)&arow[i4];
            v.x = (i4 + 0 >= bl && i4 + 0 <= t) ? __expf(r.x - m) * idv : 0.f;
            v.y = (i4 + 1 >= bl && i4 + 1 <= t) ? __expf(r.y - m) * idv : 0.f;
            v.z = (i4 + 2 >= bl && i4 + 2 <= t) ? __expf(r.z - m) * idv : 0.f;
            v.w = (i4 + 3 >= bl && i4 + 3 <= t) ? __expf(r.w - m) * idv : 0.f;
        }
        *(float4*)&arow[i4] = v;
    }
}

extern "C" void kernel_launch(void* const* d_in, const int* in_sizes, int n_in,
                              void* d_out, int out_size, void* d_ws, size_t ws_size,
                              hipStream_t stream) {
    const float* x     = (const float*)d_in[0];
    const float* Wq    = (const float*)d_in[1];
    const float* Wk    = (const float*)d_in[2];
    const float* Wv    = (const float*)d_in[3];
    const float* Wo    = (const float*)d_in[4];
    const float* gates = (const float*)d_in[5];
    const float* u     = (const float*)d_in[6];

    float* out  = (float*)d_out;                       // [T, E]
    float* attn = out + (size_t)T_LEN * EMB;           // [H, T, T]

    float* ws = (float*)d_ws;
    float* Qb = ws;
    float* Kb = Qb + (size_t)T_LEN * EMB;
    float* Vb = Kb + (size_t)T_LEN * EMB;
    float* Cb = Vb + (size_t)T_LEN * EMB;
    float* Db = Cb + (size_t)T_LEN * EMB;              // d bias [H, T]
    float* Mb = Db + (size_t)NH * T_LEN;               // row max [H, T]
    float* Ib = Mb + (size_t)NH * T_LEN;               // row 1/den [H, T]

    // fused QKV projection: blockIdx.z selects (Wq->Qb, Wk->Kb, Wv->Vb)
    gemm3_f32<<<dim3(EMB / GBN, T_LEN / GBM, 3), 256, 0, stream>>>(
        x, Wq, Wk, Wv, Qb, Kb, Vb, T_LEN, EMB, EMB);
    dbias_kernel<<<NH, 256, 0, stream>>>(Kb, u, Db);

    attn_band_kernel<<<dim3(T_LEN / 64, NH), 256, 0, stream>>>(Qb, Kb, Vb, Db, gates,
                                                               attn, Cb, Mb, Ib);
    attn_norm_kernel<<<dim3(T_LEN, NH), 256, 0, stream>>>(attn, Mb, Ib);

    // output projection
    gemm3_f32<<<dim3(EMB / GBN, T_LEN / GBM, 1), 256, 0, stream>>>(
        Cb, Wo, Wo, Wo, out, out, out, T_LEN, EMB, EMB);
}